// Round 10
// baseline (127.724 us; speedup 1.0000x reference)
//
#include <hip/hip_runtime.h>
#include <hip/hip_bf16.h>

#define NPTS 16384
#define NNBR 32
#define CIN 16
#define COUT 16
#define NBASIS 16
#define NBLK (NPTS / 16)   // 1024 blocks = 256 CU x 4 blocks/CU (co-resident)

// LDS f16 row stride 264 (528 B = 132 dw ≡ 4 mod 32): b128 reads alias 2-way (free).
#define WF_OS 264
#define ML_PS 264

// ws record layout: per point, 64 B = [x[0..15] f16 (32 B) | cx cy cz f32 | 20 B pad]
// -> BOTH Phase-B gathers (x-row + neighbor coords) hit ONE cache line.
#define CTR_BYTE_OFF (32u << 20)   // counter at ws + 32 MB, clear of the 1 MB data

typedef _Float16 half8 __attribute__((ext_vector_type(8)));
typedef float floatx4 __attribute__((ext_vector_type(4)));

// Single fused kernel. Pre-barrier: each block stages its 16 points' records
// into ws and its Wf tile into LDS. Grid barrier (device-scope, all 1024
// blocks co-resident by construction). Post-barrier: MFMA phases B and C.
__global__ __launch_bounds__(256, 4) void se3_fused_kernel(
        const float* __restrict__ input,     // (CIN, NPTS)
        const float* __restrict__ coords,    // (NPTS, 3)
        const float* __restrict__ W,         // (COUT, CIN, NBASIS)
        const float* __restrict__ centers,   // (NBASIS,)
        const float* __restrict__ mask,      // (NPTS, NNBR)
        const int* __restrict__ neighbors,   // (NPTS, NNBR)
        float* __restrict__ out,             // (COUT, NPTS)
        _Float16* __restrict__ rec16,        // ws: NPTS 64-B records
        unsigned int* __restrict__ ctr) {    // ws + 32 MB, memset to 0 pre-launch
    __shared__ _Float16 Wf[COUT * WF_OS];    // 8448 B
    __shared__ _Float16 Mld[16 * ML_PS];     // 8448 B  -> 16.9 KB total

    const int tid = threadIdx.x;
    const int t = tid & 15;
    const int p = tid >> 4;
    const int quad = (tid >> 4) & 3;
    const int wv = tid >> 6;
    const int nbase = blockIdx.x * 16;

    // ---- Stage this block's 16 records (x-row f16 + coords) into ws.
    {
        const int n = nbase + p;
        rec16[n * 32 + t] = (_Float16)input[t * NPTS + n];
        if (t < 3) ((float*)rec16)[n * 16 + 8 + t] = coords[n * 3 + t];
    }
    __syncthreads();                       // drain block's ws stores (vmcnt(0))
    if (tid == 0) {
        __builtin_amdgcn_fence(__ATOMIC_RELEASE, "agent");   // wb L2 -> coherent
        __hip_atomic_fetch_add(ctr, 1u, __ATOMIC_RELAXED, __HIP_MEMORY_SCOPE_AGENT);
    }

    // ---- Overlap the wait: stage Wf [o][b*16+i] from global W (16 KB, L2-hot).
    {
        const int o = tid >> 4, b = tid & 15;
        _Float16 w[16];
        #pragma unroll
        for (int i = 0; i < CIN; ++i) w[i] = (_Float16)W[o * 256 + i * 16 + b];
        *(half8*)&Wf[o * WF_OS + b * 16]     = *(half8*)&w[0];
        *(half8*)&Wf[o * WF_OS + b * 16 + 8] = *(half8*)&w[8];
    }

    // ---- Grid barrier: spin until all 1024 blocks arrived. Timeout = hang
    // guard only (all blocks are co-resident: 4/CU, 16.9 KB LDS, <=128 VGPR).
    if (tid == 0) {
        int iters = 0;
        while (__hip_atomic_load(ctr, __ATOMIC_RELAXED,
                                 __HIP_MEMORY_SCOPE_AGENT) < (unsigned)NBLK) {
            if (++iters > 100000) break;               // ~ms-scale guard
            __builtin_amdgcn_s_sleep(1);
        }
        __builtin_amdgcn_fence(__ATOMIC_ACQUIRE, "agent");   // inv stale L1/L2
    }
    __syncthreads();   // releases all waves; also covers Wf staging

    // ---- Phase B: wave wv -> points 4wv..4wv+3, one mfma_16x16x32_f16 each.
    // A[m=i=t][k=8q+j] = x[nbr][t]*mask_k ; B[k][n=b=t] = exp(-10(r-c_t)^2)
    const float cb = centers[t];
    #pragma unroll
    for (int q = 0; q < 4; ++q) {
        const int pq = wv * 4 + q;
        const int n = nbase + pq;
        const int kb = n * NNBR + 8 * quad;
        const int4 n0 = *(const int4*)&neighbors[kb];
        const int4 n1 = *(const int4*)&neighbors[kb + 4];
        const float4 m0 = *(const float4*)&mask[kb];
        const float4 m1 = *(const float4*)&mask[kb + 4];
        const float* cc = (const float*)&rec16[n * 32 + 16];
        const float ccx = cc[0], ccy = cc[1], ccz = cc[2];
        const int nb[8] = {n0.x & (NPTS - 1), n0.y & (NPTS - 1),
                           n0.z & (NPTS - 1), n0.w & (NPTS - 1),
                           n1.x & (NPTS - 1), n1.y & (NPTS - 1),
                           n1.z & (NPTS - 1), n1.w & (NPTS - 1)};
        const float mj[8] = {m0.x, m0.y, m0.z, m0.w, m1.x, m1.y, m1.z, m1.w};
        half8 af, bf;
        #pragma unroll
        for (int j = 0; j < 8; ++j) {
            const _Float16* xr = &rec16[nb[j] * 32];      // one 64-B line:
            const float* cr = (const float*)(xr + 16);    // x-row + coords
            const float dx = cr[0] - ccx, dy = cr[1] - ccy, dz = cr[2] - ccz;
            const float r = sqrtf(dx * dx + dy * dy + dz * dz + 1e-12f);
            const float d = r - cb;
            bf[j] = (_Float16)__expf(-10.0f * d * d);
            af[j] = (_Float16)((float)xr[t] * mj[j]);
        }
        floatx4 c = {0.0f, 0.0f, 0.0f, 0.0f};
        c = __builtin_amdgcn_mfma_f32_16x16x32_f16(af, bf, c, 0, 0, 0);
        // D[row=i=4quad+v][col=b=t] -> Mld[pq][t*16 + 4quad + v] (one b64)
        _Float16 h[4];
        #pragma unroll
        for (int v = 0; v < 4; ++v) h[v] = (_Float16)c[v];
        *(uint2*)&Mld[pq * ML_PS + t * 16 + 4 * quad] = *(uint2*)h;
    }
    __syncthreads();

    // ---- Phase C (every wave, redundant): Out = W(16x256)*Mflat(256x16).
    floatx4 acc = {0.0f, 0.0f, 0.0f, 0.0f};
    #pragma unroll
    for (int cch = 0; cch < 8; ++cch) {
        const int bi = cch * 32 + 8 * quad;
        const half8 a = *(const half8*)&Wf[t * WF_OS + bi];
        const half8 b = *(const half8*)&Mld[t * ML_PS + bi];
        acc = __builtin_amdgcn_mfma_f32_16x16x32_f16(a, b, acc, 0, 0, 0);
    }
    if (wv == (t >> 2)) {
        #pragma unroll
        for (int v = 0; v < 4; ++v)
            out[(4 * quad + v) * NPTS + nbase + t] = acc[v];
    }
}

extern "C" void kernel_launch(void* const* d_in, const int* in_sizes, int n_in,
                              void* d_out, int out_size, void* d_ws, size_t ws_size,
                              hipStream_t stream) {
    const float* input   = (const float*)d_in[0];
    const float* coords  = (const float*)d_in[1];
    const float* W       = (const float*)d_in[2];
    const float* centers = (const float*)d_in[3];
    const float* mask    = (const float*)d_in[4];
    const int*   nbr     = (const int*)d_in[5];
    float* out = (float*)d_out;
    _Float16* rec16 = (_Float16*)d_ws;
    unsigned int* ctr = (unsigned int*)((char*)d_ws + CTR_BYTE_OFF);

    // Graph-capturable memset node: barrier counter = 0 every launch.
    hipMemsetAsync(ctr, 0, sizeof(unsigned int), stream);
    se3_fused_kernel<<<NBLK, 256, 0, stream>>>(input, coords, W, centers,
                                               mask, nbr, out, rec16, ctr);
}

// Round 11
// 76.252 us; speedup vs baseline: 1.6750x; 1.6750x over previous
//
#include <hip/hip_runtime.h>
#include <hip/hip_bf16.h>

#define NPTS 16384
#define NNBR 32
#define CIN 16
#define COUT 16
#define NBASIS 16

// LDS f16 row stride 264 (528 B = 132 dw ≡ 4 mod 32): b128 reads alias 2-way (free).
#define WF_OS 264
#define ML_PS 264

typedef _Float16 half8 __attribute__((ext_vector_type(8)));
typedef float floatx4 __attribute__((ext_vector_type(4)));

// ws layout (bytes): [0,512K) xT16 f16[NPTS][16] ; [512K,520K) Wf16 f16[4096]
//                    [1M,3M)  rr   f32[NPTS*NNBR]
#define WS_XT_OFF 0
#define WS_WF_OFF (512 * 1024)
#define WS_RR_OFF (1024 * 1024)

// Prep: 2048 blocks x 256. One (n,k) pair per thread -> r (removes the
// coords gather + sqrt chain from conv). Blocks 0..63 also transpose input
// to f16 [n][i]; block 64 packs W to [o][b*16+i].
__global__ __launch_bounds__(256) void prep_kernel(
        const float* __restrict__ input, const float* __restrict__ coords,
        const float* __restrict__ W, const int* __restrict__ neighbors,
        char* __restrict__ ws) {
    const int f = blockIdx.x * 256 + threadIdx.x;   // pair id 0..524287
    const int n = f >> 5;
    const int nbr = neighbors[f] & (NPTS - 1);
    // coords[n]: shared by 32 consecutive lanes (broadcast). coords[nbr]:
    // scatter into a 196 KB L2-resident table.
    const float dx = coords[nbr * 3 + 0] - coords[n * 3 + 0];
    const float dy = coords[nbr * 3 + 1] - coords[n * 3 + 1];
    const float dz = coords[nbr * 3 + 2] - coords[n * 3 + 2];
    ((float*)(ws + WS_RR_OFF))[f] = sqrtf(dx * dx + dy * dy + dz * dz + 1e-12f);

    if (blockIdx.x < NPTS / 256) {          // transpose: 64 blocks cover NPTS
        const int n2 = blockIdx.x * 256 + threadIdx.x;
        _Float16 v[CIN];
        #pragma unroll
        for (int i = 0; i < CIN; ++i) v[i] = (_Float16)input[i * NPTS + n2];
        _Float16* xT16 = (_Float16*)(ws + WS_XT_OFF);
        *(half8*)&xT16[n2 * CIN]     = *(half8*)&v[0];
        *(half8*)&xT16[n2 * CIN + 8] = *(half8*)&v[8];
    } else if (blockIdx.x == NPTS / 256) {  // block 64: W -> [o][b*16+i] f16
        const int o = threadIdx.x >> 4, b = threadIdx.x & 15;
        _Float16 w[16];
        #pragma unroll
        for (int i = 0; i < CIN; ++i) w[i] = (_Float16)W[o * 256 + i * 16 + b];
        _Float16* wf = (_Float16*)(ws + WS_WF_OFF);
        *(half8*)&wf[o * 256 + b * 16]     = *(half8*)&w[0];
        *(half8*)&wf[o * 256 + b * 16 + 8] = *(half8*)&w[8];
    }
}

// Conv: 1024 blocks x 256 = 16 points/block. launch_bounds(256,2): allow the
// register file to hold all 4 q's of loads in flight (R10 showed the (256,4)
// build chose 32 VGPRs -> fully serialized dependency chains).
__global__ __launch_bounds__(256, 2) void se3_conv_kernel(
        const char* __restrict__ ws,
        const float* __restrict__ centers,   // (NBASIS,)
        const float* __restrict__ mask,      // (NPTS, NNBR) f32
        const int* __restrict__ neighbors,   // (NPTS, NNBR)
        float* __restrict__ out) {           // (COUT, NPTS)
    __shared__ _Float16 Wf[COUT * WF_OS];    // 8448 B
    __shared__ _Float16 Mld[16 * ML_PS];     // 8448 B

    const _Float16* xT16 = (const _Float16*)(ws + WS_XT_OFF);
    const float* rr = (const float*)(ws + WS_RR_OFF);

    const int tid = threadIdx.x;
    const int t = tid & 15;          // lane role (i in A / b in B / o in C)
    const int quad = (tid >> 4) & 3; // k-chunk select
    const int wv = tid >> 6;
    const int nbase = blockIdx.x * 16;

    // Stage Wf: 2 coalesced b128 loads + 2 b128 LDS writes per thread.
    {
        const int o = tid >> 4, ch = tid & 15;
        const _Float16* wf = (const _Float16*)(ws + WS_WF_OFF);
        const half8 w0 = *(const half8*)&wf[o * 256 + ch * 16];
        const half8 w1 = *(const half8*)&wf[o * 256 + ch * 16 + 8];
        *(half8*)&Wf[o * WF_OS + ch * 16]     = w0;
        *(half8*)&Wf[o * WF_OS + ch * 16 + 8] = w1;
    }

    const float cb = centers[t];

    // ---- Load phase: ALL per-q coalesced/broadcast loads issued up front.
    int4 n0[4], n1[4];
    float4 m0[4], m1[4], r0[4], r1[4];
    #pragma unroll
    for (int q = 0; q < 4; ++q) {
        const int kb = (nbase + wv * 4 + q) * NNBR + 8 * quad;
        n0[q] = *(const int4*)&neighbors[kb];
        n1[q] = *(const int4*)&neighbors[kb + 4];
        m0[q] = *(const float4*)&mask[kb];
        m1[q] = *(const float4*)&mask[kb + 4];
        r0[q] = *(const float4*)&rr[kb];
        r1[q] = *(const float4*)&rr[kb + 4];
    }

    // ---- Gather phase: 32 independent x loads (32 B segment per 16-lane group).
    float xg[4][8];
    #pragma unroll
    for (int q = 0; q < 4; ++q) {
        const int nb[8] = {n0[q].x & (NPTS - 1), n0[q].y & (NPTS - 1),
                           n0[q].z & (NPTS - 1), n0[q].w & (NPTS - 1),
                           n1[q].x & (NPTS - 1), n1[q].y & (NPTS - 1),
                           n1[q].z & (NPTS - 1), n1[q].w & (NPTS - 1)};
        #pragma unroll
        for (int j = 0; j < 8; ++j) xg[q][j] = (float)xT16[nb[j] * CIN + t];
    }

    // ---- Compute phase: exp chains + fragments + 4 MFMAs.
    #pragma unroll
    for (int q = 0; q < 4; ++q) {
        const float rj[8] = {r0[q].x, r0[q].y, r0[q].z, r0[q].w,
                             r1[q].x, r1[q].y, r1[q].z, r1[q].w};
        const float mj[8] = {m0[q].x, m0[q].y, m0[q].z, m0[q].w,
                             m1[q].x, m1[q].y, m1[q].z, m1[q].w};
        half8 af, bf;
        #pragma unroll
        for (int j = 0; j < 8; ++j) {
            const float d = rj[j] - cb;
            bf[j] = (_Float16)__expf(-10.0f * d * d);
            af[j] = (_Float16)(xg[q][j] * mj[j]);
        }
        floatx4 c = {0.0f, 0.0f, 0.0f, 0.0f};
        c = __builtin_amdgcn_mfma_f32_16x16x32_f16(af, bf, c, 0, 0, 0);
        // D[row=i=4quad+v][col=b=t] -> Mld[pq][t*16 + 4quad + v] (one b64)
        const int pq = wv * 4 + q;
        _Float16 h[4];
        #pragma unroll
        for (int v = 0; v < 4; ++v) h[v] = (_Float16)c[v];
        *(uint2*)&Mld[pq * ML_PS + t * 16 + 4 * quad] = *(uint2*)h;
    }
    __syncthreads();   // single barrier: Wf + Mld both cross-wave for Phase C

    // ---- Phase C (every wave, redundant): Out = W(16x256)*Mflat(256x16).
    floatx4 acc = {0.0f, 0.0f, 0.0f, 0.0f};
    #pragma unroll
    for (int cch = 0; cch < 8; ++cch) {
        const int bi = cch * 32 + 8 * quad;
        const half8 a = *(const half8*)&Wf[t * WF_OS + bi];
        const half8 b = *(const half8*)&Mld[t * ML_PS + bi];
        acc = __builtin_amdgcn_mfma_f32_16x16x32_f16(a, b, acc, 0, 0, 0);
    }
    if (wv == (t >> 2)) {
        #pragma unroll
        for (int v = 0; v < 4; ++v)
            out[(4 * quad + v) * NPTS + nbase + t] = acc[v];
    }
}

extern "C" void kernel_launch(void* const* d_in, const int* in_sizes, int n_in,
                              void* d_out, int out_size, void* d_ws, size_t ws_size,
                              hipStream_t stream) {
    const float* input   = (const float*)d_in[0];
    const float* coords  = (const float*)d_in[1];
    const float* W       = (const float*)d_in[2];
    const float* centers = (const float*)d_in[3];
    const float* mask    = (const float*)d_in[4];
    const int*   nbr     = (const int*)d_in[5];
    float* out = (float*)d_out;
    char* ws = (char*)d_ws;   // 3 MB of the 256 MB workspace

    prep_kernel<<<NPTS * NNBR / 256, 256, 0, stream>>>(input, coords, W, nbr, ws);
    se3_conv_kernel<<<NPTS / 16, 256, 0, stream>>>(ws, centers, mask, nbr, out);
}

// Round 12
// 74.371 us; speedup vs baseline: 1.7174x; 1.0253x over previous
//
#include <hip/hip_runtime.h>
#include <hip/hip_bf16.h>

#define NPTS 16384
#define NNBR 32
#define CIN 16
#define COUT 16
#define NBASIS 16

// LDS f16 row stride 264 (528 B = 132 dw ≡ 4 mod 32): b128 reads alias 2-way (free).
#define WF_OS 264
#define ML_PS 264

typedef _Float16 half8 __attribute__((ext_vector_type(8)));
typedef unsigned short ushort8 __attribute__((ext_vector_type(8)));
typedef float floatx4 __attribute__((ext_vector_type(4)));

// ws layout (f16 units): [0, NPTS*16) xT16 [n][i] ; then Wf16 [o][b*16+i]
#define WS_XT 0
#define WS_WF (NPTS * CIN)

// Prep: 64 blocks. Transpose input -> xT16 f16 [n][i]; block 0 packs W.
__global__ __launch_bounds__(256) void prep_kernel(
        const float* __restrict__ input, const float* __restrict__ W,
        _Float16* __restrict__ ws) {
    const int n = blockIdx.x * 256 + threadIdx.x;
    _Float16 v[CIN];
    #pragma unroll
    for (int i = 0; i < CIN; ++i) v[i] = (_Float16)input[i * NPTS + n];
    *(half8*)&ws[WS_XT + n * CIN]     = *(half8*)&v[0];
    *(half8*)&ws[WS_XT + n * CIN + 8] = *(half8*)&v[8];
    if (blockIdx.x == 0) {   // W -> [o][b*16+i] f16
        const int o = threadIdx.x >> 4, b = threadIdx.x & 15;
        _Float16 w[16];
        #pragma unroll
        for (int i = 0; i < CIN; ++i) w[i] = (_Float16)W[o * 256 + i * 16 + b];
        *(half8*)&ws[WS_WF + o * 256 + b * 16]     = *(half8*)&w[0];
        *(half8*)&ws[WS_WF + o * 256 + b * 16 + 8] = *(half8*)&w[8];
    }
}

// Conv: 2048 blocks x 256 threads = 8 points/block. TLP doubled vs R8
// (8 blocks/CU x 4 waves = 32 waves/CU, the max) to hide gather latency;
// per-thread chain halved (2 points/wave -> 16 gather loads). LDS 14.7 KB.
__global__ __launch_bounds__(256, 8) void se3_conv_kernel(
        const _Float16* __restrict__ ws,
        const float* __restrict__ coords,    // (NPTS, 3)
        const float* __restrict__ centers,   // (NBASIS,)
        const float* __restrict__ mask,      // (NPTS, NNBR) f32
        const int* __restrict__ neighbors,   // (NPTS, NNBR)
        float* __restrict__ out) {           // (COUT, NPTS)
    __shared__ _Float16 Wf[COUT * WF_OS];        // 8448 B
    __shared__ _Float16 Mld[8 * ML_PS];          // 4224 B
    __shared__ float    rs[8 * NNBR];            // 1024 B
    __shared__ unsigned short nb16[8 * NNBR];    //  512 B
    __shared__ _Float16 mv16[8 * NNBR];          //  512 B

    const _Float16* xT16 = &ws[WS_XT];

    const int tid = threadIdx.x;
    const int t = tid & 15;          // lane role (i in B / o in C)
    const int quad = (tid >> 4) & 3; // k-chunk select
    const int wv = tid >> 6;         // wave 0..3
    const int nbase = blockIdx.x * 8;

    // Stage Wf: 2 coalesced b128 loads + 2 b128 LDS writes per thread.
    {
        const int o = tid >> 4, ch = tid & 15;
        const half8 w0 = *(const half8*)&ws[WS_WF + o * 256 + ch * 16];
        const half8 w1 = *(const half8*)&ws[WS_WF + o * 256 + ch * 16 + 8];
        *(half8*)&Wf[o * WF_OS + ch * 16]     = w0;
        *(half8*)&Wf[o * WF_OS + ch * 16 + 8] = w1;
    }

    // ---- Phase A: one (pt,k) pair per thread. pt = tid>>5 (0..7), k = tid&31.
    // Producer wave (tid>>6) == consumer wave for pts 2wv..2wv+1 -> intra-wave.
    {
        const int pt = tid >> 5;
        const int k = tid & 31;
        const int n = nbase + pt;
        const int nbr = neighbors[n * NNBR + k] & (NPTS - 1);
        const float m = mask[n * NNBR + k];
        const float dx = coords[nbr * 3 + 0] - coords[n * 3 + 0];
        const float dy = coords[nbr * 3 + 1] - coords[n * 3 + 1];
        const float dz = coords[nbr * 3 + 2] - coords[n * 3 + 2];
        rs[tid >> 0 & 255] = 0.0f;  // placeholder overwritten below (keeps idx simple)
        rs[pt * NNBR + k] = sqrtf(dx * dx + dy * dy + dz * dz + 1e-12f);
        nb16[pt * NNBR + k] = (unsigned short)nbr;
        mv16[pt * NNBR + k] = (_Float16)m;
    }
    __syncthreads();   // Wf cross-wave (rs/nb16/mv16 are intra-wave)

    // ---- Phase B: wave wv -> points 2wv, 2wv+1; one mfma_16x16x32_f16 each.
    // A[m=i=t][k=8q+j] = x[nbr][t]*mask ; B[k][n=b=t] = exp(-10(r-c_t)^2)
    const float cb = centers[t];
    #pragma unroll
    for (int q = 0; q < 2; ++q) {
        const int pq = wv * 2 + q;
        const int kb = pq * NNBR + 8 * quad;     // group-broadcast LDS reads
        const float4 r0 = *(const float4*)&rs[kb];
        const float4 r1 = *(const float4*)&rs[kb + 4];
        const ushort8 nbv = *(const ushort8*)&nb16[kb];
        const half8 mvv = *(const half8*)&mv16[kb];
        const float rj[8] = {r0.x, r0.y, r0.z, r0.w, r1.x, r1.y, r1.z, r1.w};
        half8 af, bf;
        #pragma unroll
        for (int j = 0; j < 8; ++j) {
            const float d = rj[j] - cb;
            bf[j] = (_Float16)__expf(-10.0f * d * d);
            const float x = (float)xT16[(int)nbv[j] * CIN + t]; // 32 B/group
            af[j] = (_Float16)(x * (float)mvv[j]);
        }
        floatx4 c = {0.0f, 0.0f, 0.0f, 0.0f};
        c = __builtin_amdgcn_mfma_f32_16x16x32_f16(af, bf, c, 0, 0, 0);
        // D[row=i=4quad+v][col=b=t] -> Mld[pq][t*16 + 4quad + v] (one b64)
        _Float16 h[4];
        #pragma unroll
        for (int v = 0; v < 4; ++v) h[v] = (_Float16)c[v];
        *(uint2*)&Mld[pq * ML_PS + t * 16 + 4 * quad] = *(uint2*)h;
    }
    __syncthreads();

    // ---- Phase C (every wave, redundant): Out = W(16x256) * Mflat(256x8).
    // A[m=o=t][bi-chunk]; B[bi-chunk][n=pt=t] valid for t<8 (cols 8-15 zero).
    floatx4 acc = {0.0f, 0.0f, 0.0f, 0.0f};
    #pragma unroll
    for (int cch = 0; cch < 8; ++cch) {
        const int bi = cch * 32 + 8 * quad;
        const half8 a = *(const half8*)&Wf[t * WF_OS + bi];
        half8 b = {};
        if (t < 8) b = *(const half8*)&Mld[t * ML_PS + bi];
        acc = __builtin_amdgcn_mfma_f32_16x16x32_f16(a, b, acc, 0, 0, 0);
    }
    // D[row=o=4quad+v][col=pt=t]; wave wv stores cols 2wv, 2wv+1.
    if (t < 8 && wv == (t >> 1)) {
        #pragma unroll
        for (int v = 0; v < 4; ++v)
            out[(4 * quad + v) * NPTS + nbase + t] = acc[v];
    }
}

extern "C" void kernel_launch(void* const* d_in, const int* in_sizes, int n_in,
                              void* d_out, int out_size, void* d_ws, size_t ws_size,
                              hipStream_t stream) {
    const float* input   = (const float*)d_in[0];
    const float* coords  = (const float*)d_in[1];
    const float* W       = (const float*)d_in[2];
    const float* centers = (const float*)d_in[3];
    const float* mask    = (const float*)d_in[4];
    const int*   nbr     = (const int*)d_in[5];
    float* out = (float*)d_out;
    _Float16* ws = (_Float16*)d_ws;   // ~520 KB of the 256 MB workspace

    prep_kernel<<<NPTS / 256, 256, 0, stream>>>(input, W, ws);
    se3_conv_kernel<<<NPTS / 8, 256, 0, stream>>>(ws, coords, centers, mask,
                                                  nbr, out);
}

// Round 13
// 74.195 us; speedup vs baseline: 1.7215x; 1.0024x over previous
//
#include <hip/hip_runtime.h>
#include <hip/hip_bf16.h>

#define NPTS 16384
#define NNBR 32
#define CIN 16
#define COUT 16
#define NBASIS 16

// LDS f16 row stride 264 (528 B = 132 dw ≡ 4 mod 32): b128 reads alias 2-way (free).
#define WF_OS 264
#define ML_PS 264

typedef _Float16 half8 __attribute__((ext_vector_type(8)));
typedef _Float16 half4 __attribute__((ext_vector_type(4)));
typedef unsigned short ushort8 __attribute__((ext_vector_type(8)));
typedef float floatx4 __attribute__((ext_vector_type(4)));

// ws layout (f16 units): [0, NPTS*16) xT16 [n][i] ; then Wf16 [o][b*16+i]
#define WS_XT 0
#define WS_WF (NPTS * CIN)

// Prep: 256 blocks x 256 threads (full-chip spread; R12 used 64 blocks = 1/4
// of the CUs). Thread = (point-in-block p4 = tid>>2, channel-quad c4 = tid&3):
// reads input[c4*4+j][n] (coalesced along n within each lane-group), writes
// one contiguous 8 B f16x4. Block 0 additionally packs W -> [o][b*16+i].
__global__ __launch_bounds__(256) void prep_kernel(
        const float* __restrict__ input, const float* __restrict__ W,
        _Float16* __restrict__ ws) {
    const int p4 = threadIdx.x >> 2;          // 0..63 point within block
    const int c4 = threadIdx.x & 3;           // channel quad
    const int n = blockIdx.x * 64 + p4;
    half4 v;
    #pragma unroll
    for (int j = 0; j < 4; ++j)
        v[j] = (_Float16)input[(c4 * 4 + j) * NPTS + n];
    *(half4*)&ws[WS_XT + n * CIN + c4 * 4] = v;
    if (blockIdx.x == 0) {   // W -> [o][b*16+i] f16
        const int o = threadIdx.x >> 4, b = threadIdx.x & 15;
        _Float16 w[16];
        #pragma unroll
        for (int i = 0; i < CIN; ++i) w[i] = (_Float16)W[o * 256 + i * 16 + b];
        *(half8*)&ws[WS_WF + o * 256 + b * 16]     = *(half8*)&w[0];
        *(half8*)&ws[WS_WF + o * 256 + b * 16 + 8] = *(half8*)&w[8];
    }
}

// Conv (R12 best-measured structure): 2048 blocks x 256 = 8 points/block.
// 8 blocks/CU x 4 waves = 32 waves/CU (max TLP). LDS 14.7 KB.
__global__ __launch_bounds__(256, 8) void se3_conv_kernel(
        const _Float16* __restrict__ ws,
        const float* __restrict__ coords,    // (NPTS, 3)
        const float* __restrict__ centers,   // (NBASIS,)
        const float* __restrict__ mask,      // (NPTS, NNBR) f32
        const int* __restrict__ neighbors,   // (NPTS, NNBR)
        float* __restrict__ out) {           // (COUT, NPTS)
    __shared__ _Float16 Wf[COUT * WF_OS];        // 8448 B
    __shared__ _Float16 Mld[8 * ML_PS];          // 4224 B
    __shared__ float    rs[8 * NNBR];            // 1024 B
    __shared__ unsigned short nb16[8 * NNBR];    //  512 B
    __shared__ _Float16 mv16[8 * NNBR];          //  512 B

    const _Float16* xT16 = &ws[WS_XT];

    const int tid = threadIdx.x;
    const int t = tid & 15;          // lane role (i in B / o in C)
    const int quad = (tid >> 4) & 3; // k-chunk select
    const int wv = tid >> 6;         // wave 0..3
    const int nbase = blockIdx.x * 8;

    // Stage Wf: 2 coalesced b128 loads + 2 b128 LDS writes per thread.
    {
        const int o = tid >> 4, ch = tid & 15;
        const half8 w0 = *(const half8*)&ws[WS_WF + o * 256 + ch * 16];
        const half8 w1 = *(const half8*)&ws[WS_WF + o * 256 + ch * 16 + 8];
        *(half8*)&Wf[o * WF_OS + ch * 16]     = w0;
        *(half8*)&Wf[o * WF_OS + ch * 16 + 8] = w1;
    }

    // ---- Phase A: one (pt,k) pair per thread. pt = tid>>5, k = tid&31.
    // Producer wave == consumer wave for pts 2wv..2wv+1 -> intra-wave RAW.
    {
        const int pt = tid >> 5;
        const int k = tid & 31;
        const int n = nbase + pt;
        const int nbr = neighbors[n * NNBR + k] & (NPTS - 1);
        const float m = mask[n * NNBR + k];
        const float dx = coords[nbr * 3 + 0] - coords[n * 3 + 0];
        const float dy = coords[nbr * 3 + 1] - coords[n * 3 + 1];
        const float dz = coords[nbr * 3 + 2] - coords[n * 3 + 2];
        rs[pt * NNBR + k] = sqrtf(dx * dx + dy * dy + dz * dz + 1e-12f);
        nb16[pt * NNBR + k] = (unsigned short)nbr;
        mv16[pt * NNBR + k] = (_Float16)m;
    }
    __syncthreads();   // Wf cross-wave (rs/nb16/mv16 are intra-wave)

    // ---- Phase B: wave wv -> points 2wv, 2wv+1; one mfma_16x16x32_f16 each.
    // A[m=i=t][k=8q+j] = x[nbr][t]*mask ; B[k][n=b=t] = exp(-10(r-c_t)^2)
    const float cb = centers[t];
    #pragma unroll
    for (int q = 0; q < 2; ++q) {
        const int pq = wv * 2 + q;
        const int kb = pq * NNBR + 8 * quad;     // group-broadcast LDS reads
        const float4 r0 = *(const float4*)&rs[kb];
        const float4 r1 = *(const float4*)&rs[kb + 4];
        const ushort8 nbv = *(const ushort8*)&nb16[kb];
        const half8 mvv = *(const half8*)&mv16[kb];
        const float rj[8] = {r0.x, r0.y, r0.z, r0.w, r1.x, r1.y, r1.z, r1.w};
        half8 af, bf;
        #pragma unroll
        for (int j = 0; j < 8; ++j) {
            const float d = rj[j] - cb;
            bf[j] = (_Float16)__expf(-10.0f * d * d);
            const float x = (float)xT16[(int)nbv[j] * CIN + t]; // 32 B/group
            af[j] = (_Float16)(x * (float)mvv[j]);
        }
        floatx4 c = {0.0f, 0.0f, 0.0f, 0.0f};
        c = __builtin_amdgcn_mfma_f32_16x16x32_f16(af, bf, c, 0, 0, 0);
        // D[row=i=4quad+v][col=b=t] -> Mld[pq][t*16 + 4quad + v] (one b64)
        _Float16 h[4];
        #pragma unroll
        for (int v = 0; v < 4; ++v) h[v] = (_Float16)c[v];
        *(uint2*)&Mld[pq * ML_PS + t * 16 + 4 * quad] = *(uint2*)h;
    }
    __syncthreads();

    // ---- Phase C (every wave, redundant): Out = W(16x256) * Mflat(256x8).
    // A[m=o=t][bi-chunk]; B[bi-chunk][n=pt=t] valid for t<8 (cols 8-15 zero).
    floatx4 acc = {0.0f, 0.0f, 0.0f, 0.0f};
    #pragma unroll
    for (int cch = 0; cch < 8; ++cch) {
        const int bi = cch * 32 + 8 * quad;
        const half8 a = *(const half8*)&Wf[t * WF_OS + bi];
        half8 b = {};
        if (t < 8) b = *(const half8*)&Mld[t * ML_PS + bi];
        acc = __builtin_amdgcn_mfma_f32_16x16x32_f16(a, b, acc, 0, 0, 0);
    }
    // D[row=o=4quad+v][col=pt=t]; wave wv stores cols 2wv, 2wv+1.
    if (t < 8 && wv == (t >> 1)) {
        #pragma unroll
        for (int v = 0; v < 4; ++v)
            out[(4 * quad + v) * NPTS + nbase + t] = acc[v];
    }
}

extern "C" void kernel_launch(void* const* d_in, const int* in_sizes, int n_in,
                              void* d_out, int out_size, void* d_ws, size_t ws_size,
                              hipStream_t stream) {
    const float* input   = (const float*)d_in[0];
    const float* coords  = (const float*)d_in[1];
    const float* W       = (const float*)d_in[2];
    const float* centers = (const float*)d_in[3];
    const float* mask    = (const float*)d_in[4];
    const int*   nbr     = (const int*)d_in[5];
    float* out = (float*)d_out;
    _Float16* ws = (_Float16*)d_ws;   // ~520 KB of the 256 MB workspace

    prep_kernel<<<NPTS / 64, 256, 0, stream>>>(input, W, ws);
    se3_conv_kernel<<<NPTS / 8, 256, 0, stream>>>(ws, coords, centers, mask,
                                                  nbr, out);
}